// Round 9
// baseline (165.602 us; speedup 1.0000x reference)
//
#include <hip/hip_runtime.h>
#include <math.h>

#define B_SZ 1024

typedef __attribute__((ext_vector_type(8))) short bf16x8;
typedef __attribute__((ext_vector_type(4))) float f32x4;
typedef __attribute__((ext_vector_type(4))) float floatx4;
typedef __attribute__((ext_vector_type(4))) unsigned short ushortx4;

#define GLOAD16(src, dst) __builtin_amdgcn_global_load_lds( \
    (const __attribute__((address_space(1))) void*)(src), \
    (__attribute__((address_space(3))) void*)(dst), 16, 0, 0)

__device__ __forceinline__ unsigned short f2bf(float f) {
  unsigned int u = __float_as_uint(f);
  u += 0x7fff + ((u >> 16) & 1);
  return (unsigned short)(u >> 16);
}
__device__ __forceinline__ float bf2f(unsigned short b) {
  return __uint_as_float(((unsigned int)b) << 16);
}
__device__ __forceinline__ float gelu_exact(float x) {
  return 0.5f * x * (1.0f + erff(x * 0.70710678118654752f));
}
__device__ __forceinline__ float gelu_fast(float x) {
  const float c0 = 2.3022586f;
  const float c1 = 0.10295465f;
  float z = x * __builtin_fmaf(x * x, c1, c0);
  float e = __builtin_amdgcn_exp2f(z);
  float r = __builtin_amdgcn_rcpf(e + 1.0f);
  return __builtin_fmaf(-x, r, x);
}
__device__ __forceinline__ float wred(float v) {
#pragma unroll
  for (int o = 32; o > 0; o >>= 1) v += __shfl_xor(v, o, 64);
  return v;
}

// ---------------- merged prep: 10 transpose jobs + Amat + stats + bcat ----------------
struct PrepArgs {
  const float* src[10];
  unsigned short* dst[10];
  int ldin[10]; int coff[10]; int Nsrc[10]; int Ksrc[10]; int Kp[10];
  int nbx[10]; int blk0[11];
};

__global__ __launch_bounds__(256)
void prep_all(PrepArgs J,
              const float* __restrict__ tok_w, const float* __restrict__ tok_b,
              const float* __restrict__ cat_emb,
              const float* __restrict__ ln_g, const float* __restrict__ ln_b,
              const float* __restrict__ r_b1, const float* __restrict__ a_b1,
              const float* __restrict__ gh_b1, const float* __restrict__ ex_b1,
              unsigned short* __restrict__ Amat,
              float* __restrict__ nstat, float* __restrict__ cstat,
              float* __restrict__ bcat)
{
  const int bid = blockIdx.x;
  const int tid = threadIdx.x;
  const int lane = tid & 63;
  const int NT = J.blk0[10];                 // 1328
  if (bid < NT) {
    __shared__ float tile[64][65];
    int j = 0;
    while (bid >= J.blk0[j + 1]) ++j;
    const int bx = bid - J.blk0[j];
    const int k0 = (bx % J.nbx[j]) * 64;
    const int n0 = (bx / J.nbx[j]) * 64;
    const float* in = J.src[j];
    unsigned short* out = J.dst[j];
    const int ldin = J.ldin[j], coff = J.coff[j], Nsrc = J.Nsrc[j], Ksrc = J.Ksrc[j], Kp = J.Kp[j];
    const int kx = tid & 63;
    const int ry = tid >> 6;
    for (int r = ry; r < 64; r += 4) {
      const int k = k0 + r;
      const int n = n0 + kx;
      tile[r][kx] = (k < Ksrc && n < Nsrc) ? in[(size_t)k * ldin + coff + n] : 0.f;
    }
    __syncthreads();
    for (int r = ry; r < 64; r += 4) {
      const int n = n0 + r;
      const int k = k0 + kx;
      out[(size_t)n * Kp + k] = f2bf(tile[kx][r]);
    }
  } else if (bid < NT + 576) {
    const int r = (bid - NT) * 4 + (tid >> 6);
    if (r >= 2304) return;
    unsigned short* out = Amat + (size_t)r * 1024;
    for (int k = lane * 4; k < 1024; k += 256) {
      floatx4 g = *(const floatx4*)(ln_g + k);
      floatx4 v;
      if (r <= 100) {
        floatx4 a = *(const floatx4*)(tok_w + (size_t)r * 1024 + k);
#pragma unroll
        for (int q = 0; q < 4; q++) v[q] = a[q] * g[q];
      } else if (r <= 200) {
        floatx4 a = *(const floatx4*)(tok_b + (size_t)(r - 101) * 1024 + k);
#pragma unroll
        for (int q = 0; q < 4; q++) v[q] = a[q] * g[q];
      } else if (r <= 2200) {
        const int j = r - 201;
        const int c = j / 100;
        floatx4 a = *(const floatx4*)(cat_emb + (size_t)j * 1024 + k);
        floatx4 bq = *(const floatx4*)(tok_b + (size_t)(100 + c) * 1024 + k);
#pragma unroll
        for (int q = 0; q < 4; q++) v[q] = (a[q] + bq[q]) * g[q];
      } else if (r == 2201) {
        v = g;
      } else if (r == 2202) {
        v = *(const floatx4*)(ln_b + k);
      } else {
        v[0] = 0.f; v[1] = 0.f; v[2] = 0.f; v[3] = 0.f;
      }
      ushortx4 o;
#pragma unroll
      for (int q = 0; q < 4; q++) o[q] = f2bf(v[q]);
      *(ushortx4*)(out + k) = o;
    }
  } else if (bid < NT + 576 + 526) {
    const int w = (bid - NT - 576) * 4 + (tid >> 6);
    if (w >= 2101) return;
    if (w <= 100) {
      const int t = w;
      const float* wr = tok_w + (size_t)t * 1024;
      const float* br = (t >= 1) ? (tok_b + (size_t)(t - 1) * 1024) : nullptr;
      float sw = 0, sww = 0, sb = 0, sbb = 0, swb = 0;
      for (int k = lane * 4; k < 1024; k += 256) {
        floatx4 a = *(const floatx4*)(wr + k);
#pragma unroll
        for (int q = 0; q < 4; q++) { sw += a[q]; sww += a[q] * a[q]; }
        if (br) {
          floatx4 bq = *(const floatx4*)(br + k);
#pragma unroll
          for (int q = 0; q < 4; q++) { sb += bq[q]; sbb += bq[q] * bq[q]; swb += a[q] * bq[q]; }
        }
      }
      sw = wred(sw); sww = wred(sww); sb = wred(sb); sbb = wred(sbb); swb = wred(swb);
      if (lane == 0) {
        float* ns = nstat + (size_t)t * 5;
        ns[0] = sw; ns[1] = sww; ns[2] = sb; ns[3] = sbb; ns[4] = swb;
      }
    } else {
      const int j = w - 101;
      const int c = j / 100;
      const float* ar = cat_emb + (size_t)j * 1024;
      const float* br = tok_b + (size_t)(100 + c) * 1024;
      float s1 = 0, s2 = 0;
      for (int k = lane * 4; k < 1024; k += 256) {
        floatx4 a = *(const floatx4*)(ar + k);
        floatx4 bq = *(const floatx4*)(br + k);
#pragma unroll
        for (int q = 0; q < 4; q++) { const float v = a[q] + bq[q]; s1 += v; s2 += v * v; }
      }
      s1 = wred(s1); s2 = wred(s2);
      if (lane == 0) { cstat[(size_t)j * 2] = s1; cstat[(size_t)j * 2 + 1] = s2; }
    }
  } else {
    const int n = (bid - NT - 1102) * 256 + tid;
    if (n >= 3072) return;
    float v;
    if (n < 256) v = r_b1[n];
    else if (n < 512) v = a_b1[n - 256];
    else if (n < 1024) v = gh_b1[n - 512];
    else v = ex_b1[n - 1024];
    bcat[n] = v;
  }
}

// ---------------- 64x64-tile bf16 GEMM body (256 thr, 4 waves, high blocks/CU) ----------------
// EPI 0: f32 out = acc+bias+extra ; 1: bf16 relu(acc+bias) ; 3: f32 acc
template<int EPI>
__device__ __forceinline__
void gemm64_body(int bid, const unsigned short* __restrict__ A, long pitchA,
                 const unsigned short* __restrict__ Bw, int K,
                 const float* __restrict__ bias, const float* __restrict__ extra,
                 int NB, int Nvalid, int ldo,
                 float* __restrict__ outf, unsigned short* __restrict__ outb)
{
  __shared__ unsigned short As[64 * 32];
  __shared__ unsigned short Bs[64 * 32];
  const int tid = threadIdx.x, lane = tid & 63, wv = tid >> 6;
  const int nb = bid % NB, mb = bid / NB;
  const int m0 = mb * 64, n0 = nb * 64;
  const int wr = (wv >> 1) << 5, wc = (wv & 1) << 5;
  const int fr = lane & 15, fq = lane >> 4;

  const unsigned short* srcA = A + (size_t)(m0 + (tid >> 2)) * pitchA + ((tid & 3) << 3);
  const unsigned short* srcB = Bw + (size_t)(n0 + (tid >> 2)) * K + ((tid & 3) << 3);

  f32x4 acc[2][2] = {};
  for (int k0 = 0; k0 < K; k0 += 32) {
    __syncthreads();
    GLOAD16(srcA + k0, &As[tid * 8]);
    GLOAD16(srcB + k0, &Bs[tid * 8]);
    __syncthreads();
    bf16x8 af[2], bw_[2];
#pragma unroll
    for (int i = 0; i < 2; i++) {
      af[i]  = *(const bf16x8*)&As[(wr + i * 16 + fr) * 32 + fq * 8];
      bw_[i] = *(const bf16x8*)&Bs[(wc + i * 16 + fr) * 32 + fq * 8];
    }
#pragma unroll
    for (int i = 0; i < 2; i++)
#pragma unroll
      for (int j = 0; j < 2; j++)
        acc[i][j] = __builtin_amdgcn_mfma_f32_16x16x32_bf16(af[i], bw_[j], acc[i][j], 0, 0, 0);
  }

#pragma unroll
  for (int i = 0; i < 2; i++)
#pragma unroll
    for (int j = 0; j < 2; j++) {
      const int n = n0 + wc + j * 16 + fr;
      if (n >= ldo) continue;
      const bool valid = (n < Nvalid);
      const float bv = (EPI == 3) ? 0.f : (valid ? bias[n] : 0.f);
      const float ev = (EPI == 0) ? extra[n] : 0.f;
#pragma unroll
      for (int q = 0; q < 4; q++) {
        const int m = m0 + wr + i * 16 + fq * 4 + q;
        const float a = acc[i][j][q];
        if (EPI == 0) {
          outf[(size_t)m * ldo + n] = a + bv + ev;
        } else if (EPI == 1) {
          outb[(size_t)m * ldo + n] = f2bf(fmaxf(a + bv, 0.f));
        } else {
          outf[(size_t)m * ldo + n] = a;
        }
      }
    }
}

template<int EPI>
__global__ __launch_bounds__(256)
void gemm64(const unsigned short* __restrict__ A, long pitchA,
            const unsigned short* __restrict__ Bw, int K,
            const float* __restrict__ bias, const float* __restrict__ extra,
            int NB, int Nvalid, int ldo,
            float* __restrict__ outf, unsigned short* __restrict__ outb)
{
  gemm64_body<EPI>(blockIdx.x, A, pitchA, Bw, K, bias, extra, NB, Nvalid, ldo, outf, outb);
}

// ---------------- u_const body ----------------
__device__ __forceinline__
void u_const_body(int bid, const unsigned short* __restrict__ w0u, const float* __restrict__ nstat,
                  const float* __restrict__ tok_w, const float* __restrict__ ln_g,
                  const float* __restrict__ ln_b, const float* __restrict__ lin0_b,
                  float* __restrict__ ucon)
{
  __shared__ float xk[1024];
  const int tid = threadIdx.x, lane = tid & 63, wv = tid >> 6;
  const float m = nstat[0] * (1.f / 1024.f);
  const float ex2 = nstat[1] * (1.f / 1024.f);
  const float rs = rsqrtf(ex2 - m * m + 1e-5f);
  for (int k = tid; k < 1024; k += 256)
    xk[k] = bf2f(f2bf((tok_w[k] - m) * rs * ln_g[k] + ln_b[k]));
  __syncthreads();
  const int c = bid * 4 + wv;
  if (c >= 704) return;
  if (c >= 675) { if (lane == 0) ucon[c] = 0.f; return; }
  const unsigned short* wr = w0u + (size_t)c * 1024;
  float s = 0.f;
  for (int k = lane; k < 1024; k += 64) s += bf2f(wr[k]) * xk[k];
  s = wred(s);
  if (lane == 0) ucon[c] = gelu_exact(s + lin0_b[c]);
}

// table GEMM (64x64 tiles: 432 blocks) + u_const (176 blocks)
__global__ __launch_bounds__(256)
void tab_and_u(const unsigned short* __restrict__ Amat, const unsigned short* __restrict__ w0v,
               float* __restrict__ TAB,
               const unsigned short* __restrict__ w0u, const float* __restrict__ nstat,
               const float* __restrict__ tok_w, const float* __restrict__ ln_g,
               const float* __restrict__ ln_b, const float* __restrict__ lin0_b,
               float* __restrict__ ucon)
{
  if (blockIdx.x < 432)
    gemm64_body<3>(blockIdx.x, Amat, 1024, w0v, 1024, nullptr, nullptr, 12, 768, 768, TAB, nullptr);
  else
    u_const_body(blockIdx.x - 432, w0u, nstat, tok_w, ln_g, ln_b, lin0_b, ucon);
}

// ---------------- input-independent rows + wss ----------------
__global__ __launch_bounds__(256)
void cat_rows(const float* __restrict__ TAB, const float* __restrict__ nstat,
              const float* __restrict__ cstat, const float* __restrict__ lin0_b,
              const float* __restrict__ sgu_w,
              float* __restrict__ catval, float* __restrict__ catsc,
              float* __restrict__ wss_g)
{
  const int r = blockIdx.x * 4 + (threadIdx.x >> 6);
  const int lane = threadIdx.x & 63;
  if (r == 2001) {
    float s = (lane < 121) ? sgu_w[lane] : 0.f;
    if (lane + 64 < 121) s += sgu_w[lane + 64];
    s = wred(s);
    if (lane == 0) wss_g[0] = s;
    return;
  }
  if (r > 2001) return;
  float m, ex2;
  const float* T1;
  if (r < 2000) {
    m = cstat[(size_t)r * 2] * (1.f / 1024.f);
    ex2 = cstat[(size_t)r * 2 + 1] * (1.f / 1024.f);
    T1 = TAB + (size_t)(201 + r) * 768;
  } else {
    m = nstat[0] * (1.f / 1024.f);
    ex2 = nstat[1] * (1.f / 1024.f);
    T1 = TAB;
  }
  const float rs = rsqrtf(ex2 - m * m + 1e-5f);
  const float ga = -m * rs;
  const float* R = TAB + (size_t)2201 * 768;
  const float* C = TAB + (size_t)2202 * 768;
  const int dl = lane << 2;
  float s = 0.f, ss = 0.f;
  float* outp = catval + (size_t)r * 768;
#pragma unroll
  for (int ch = 0; ch < 3; ch++) {
    const int d = ch * 256 + dl;
    floatx4 t1 = *(const floatx4*)(T1 + d);
    floatx4 rr = *(const floatx4*)(R + d);
    floatx4 cc = *(const floatx4*)(C + d);
    floatx4 o;
#pragma unroll
    for (int q = 0; q < 4; q++) {
      const int dd = d + q;
      const float c2 = (dd < 675) ? (cc[q] + lin0_b[675 + dd]) : 0.f;
      const float pre = __builtin_fmaf(rs, t1[q], __builtin_fmaf(ga, rr[q], c2));
      const float g = (dd < 675) ? gelu_fast(pre) : 0.f;
      o[q] = g; s += g; ss = __builtin_fmaf(g, g, ss);
    }
    *(floatx4*)(outp + d) = o;
  }
  s = wred(s); ss = wred(ss);
  const float mu = s * (1.f / 675.f);
  const float rho = rsqrtf(ss * (1.f / 675.f) - mu * mu + 1e-5f);
  if (lane == 0) { catsc[(size_t)r * 2] = mu; catsc[(size_t)r * 2 + 1] = rho; }
}

// ---------------- fused v-path v5: 256 thr / 4 waves / ~20KB LDS -> 8 blocks/CU ----------------
__global__ __launch_bounds__(256, 8)
void fused_v5(const float* __restrict__ TAB, const float* __restrict__ nstat,
              const float* __restrict__ catsc, const float* __restrict__ catval,
              const float* __restrict__ x_num, const int* __restrict__ x_cat,
              const float* __restrict__ sgu_ln_g, const float* __restrict__ sgu_ln_b,
              const float* __restrict__ sgu_w, const float* __restrict__ sgu_b,
              const float* __restrict__ lin0_b, const float* __restrict__ ucon,
              const float* __restrict__ wss_g,
              unsigned short* __restrict__ uv)
{
  const int b = blockIdx.x;
  const int tid = threadIdx.x, lane = tid & 63, wv = tid >> 6;
  __shared__ float Rls[768], Cls[768];
  __shared__ float alf[100], bet[100], gam[100], swt[100];
  __shared__ float wrc[21], catkb[21];
  __shared__ int catrowS[21];
  __shared__ float accw[4][768];
  __shared__ float kbw[4];

  for (int d = tid; d < 768; d += 256) {
    Rls[d] = (d < 675) ? TAB[(size_t)2201 * 768 + d] : 0.f;
    Cls[d] = (d < 675) ? (TAB[(size_t)2202 * 768 + d] + lin0_b[675 + d]) : 0.f;
  }
  if (tid < 100) {
    const int tt = tid;
    const float sc = x_num[b * 100 + tt];
    const float* ns = nstat + (size_t)(tt + 1) * 5;
    const float m = (sc * ns[0] + ns[2]) * (1.f / 1024.f);
    const float ex2 = (sc * sc * ns[1] + 2.f * sc * ns[4] + ns[3]) * (1.f / 1024.f);
    const float rs = rsqrtf(ex2 - m * m + 1e-5f);
    alf[tt] = rs * sc; bet[tt] = rs; gam[tt] = -m * rs;
    swt[tt] = sgu_w[tt + 1];
  } else if (tid < 121) {
    const int ii = tid - 100;
    int row; float sw;
    if (ii < 20) { row = x_cat[b * 20 + ii] + 100 * ii; sw = sgu_w[101 + ii]; }
    else { row = 2000; sw = sgu_w[0]; }
    const float mu = catsc[(size_t)row * 2], rho = catsc[(size_t)row * 2 + 1];
    const float wr = sw * rho;
    wrc[ii] = wr; catkb[ii] = wr * mu; catrowS[ii] = row;
  }
  __syncthreads();

  float acc[12] = {};
  float kb = 0.f;
  const int dl = lane << 2;

  for (int i = 0; i < 13; i++) {
    const int tA = wv + 8 * i;
    if (tA >= 100) break;
    const int tB = tA + 4;
    const bool hB = (tB < 100);
    const int tBs = hB ? tB : tA;
    const float aA = alf[tA], eA = bet[tA], gA = gam[tA];
    const float aB = alf[tBs], eB = bet[tBs], gB = gam[tBs];
    const float* T1A = TAB + (size_t)(tA + 1) * 768;
    const float* T2A = TAB + (size_t)(101 + tA) * 768;
    const float* T1B = TAB + (size_t)(tBs + 1) * 768;
    const float* T2B = TAB + (size_t)(101 + tBs) * 768;
    float vA[12], vB[12];
    float sA = 0.f, qA = 0.f, sB = 0.f, qB = 0.f;
#pragma unroll
    for (int ch = 0; ch < 3; ch++) {
      const int d = ch * 256 + dl;
      floatx4 t1a = *(const floatx4*)(T1A + d);
      floatx4 t2a = *(const floatx4*)(T2A + d);
      floatx4 t1b = *(const floatx4*)(T1B + d);
      floatx4 t2b = *(const floatx4*)(T2B + d);
      floatx4 rr = *(const floatx4*)(&Rls[d]);
      floatx4 cc = *(const floatx4*)(&Cls[d]);
#pragma unroll
      for (int q = 0; q < 4; q++) {
        const float g0 = gelu_fast(__builtin_fmaf(aA, t1a[q], __builtin_fmaf(eA, t2a[q], __builtin_fmaf(gA, rr[q], cc[q]))));
        vA[ch * 4 + q] = g0; sA += g0; qA = __builtin_fmaf(g0, g0, qA);
        const float g1 = gelu_fast(__builtin_fmaf(aB, t1b[q], __builtin_fmaf(eB, t2b[q], __builtin_fmaf(gB, rr[q], cc[q]))));
        vB[ch * 4 + q] = g1; sB += g1; qB = __builtin_fmaf(g1, g1, qB);
      }
    }
    sA = wred(sA); qA = wred(qA); sB = wred(sB); qB = wred(qB);
    const float swA = swt[tA];
    const float swB = hB ? swt[tBs] : 0.f;
    const float muA = sA * (1.f / 675.f);
    const float wA = swA * rsqrtf(qA * (1.f / 675.f) - muA * muA + 1e-5f);
    const float muB = sB * (1.f / 675.f);
    const float wB = swB * rsqrtf(qB * (1.f / 675.f) - muB * muB + 1e-5f);
#pragma unroll
    for (int q = 0; q < 12; q++)
      acc[q] = __builtin_fmaf(wA, vA[q], __builtin_fmaf(wB, vB[q], acc[q]));
    kb = __builtin_fmaf(wA, muA, __builtin_fmaf(wB, muB, kb));
  }

  // gather precomputed cat + t0 rows (21 rows over 4 waves)
  for (int i = 0; i < 6; i++) {
    const int ii = wv + 4 * i;
    if (ii >= 21) break;
    const float wr = wrc[ii];
    const float* cv = catval + (size_t)catrowS[ii] * 768;
#pragma unroll
    for (int ch = 0; ch < 3; ch++) {
      floatx4 v = *(const floatx4*)(cv + ch * 256 + dl);
#pragma unroll
      for (int q = 0; q < 4; q++) acc[ch * 4 + q] = __builtin_fmaf(wr, v[q], acc[ch * 4 + q]);
    }
  }
  if (lane == 0) kbw[wv] = kb;

#pragma unroll
  for (int ch = 0; ch < 3; ch++)
    *(floatx4*)&accw[wv][ch * 256 + dl] = *(const floatx4*)&acc[ch * 4];
  __syncthreads();

  float kbs = kbw[0] + kbw[1] + kbw[2] + kbw[3];
#pragma unroll
  for (int i = 0; i < 21; i++) kbs += catkb[i];
  const float sb0 = sgu_b[0];
  const float wss = wss_g[0];
  for (int d = tid; d < 704; d += 256) {
    unsigned short o = 0;
    if (d < 675) {
      const float a = accw[0][d] + accw[1][d] + accw[2][d] + accw[3][d];
      const float v0 = sgu_ln_g[d] * (a - kbs) + sgu_ln_b[d] * wss + sb0;
      o = f2bf(ucon[d] * v0);
    }
    uv[(size_t)b * 704 + d] = o;
  }
}

// ---------------- LN + gelu -> hidden bf16 + fused base dot ----------------
__global__ __launch_bounds__(256)
void ln_gelu_hidden(const float* __restrict__ xfin,
                    const float* __restrict__ ln_g, const float* __restrict__ ln_b,
                    const float* __restrict__ base_w,
                    unsigned short* __restrict__ hid_bf, float* __restrict__ base_y)
{
  const int w = (blockIdx.x * 256 + threadIdx.x) >> 6;
  const int lane = threadIdx.x & 63;
  if (w >= B_SZ) return;
  const float* row = xfin + (size_t)w * 1024;
  float s = 0.f, ss = 0.f;
  for (int k = lane; k < 1024; k += 64) { float v = row[k]; s += v; ss += v * v; }
  s = wred(s); ss = wred(ss);
  const float m = s * (1.f / 1024.f);
  const float var = ss * (1.f / 1024.f) - m * m;
  const float rs = rsqrtf(var + 1e-5f);
  float bacc = 0.f;
  for (int k = lane; k < 1024; k += 64) {
    float v = gelu_fast((row[k] - m) * rs * ln_g[k] + ln_b[k]);
    hid_bf[(size_t)w * 1024 + k] = f2bf(v);
    bacc = __builtin_fmaf(v, base_w[k], bacc);
  }
  bacc = wred(bacc);
  if (lane == 0) base_y[w] = bacc;
}

// ---------------- per-row finale ----------------
__global__ __launch_bounds__(256)
void final_head(const unsigned short* __restrict__ H1, const float* __restrict__ base_y,
                const float* __restrict__ r_w2, const float* __restrict__ r_b2,
                const float* __restrict__ a_w2, const float* __restrict__ a_b2,
                const float* __restrict__ gh_w2, const float* __restrict__ gh_b2,
                const float* __restrict__ ex_w2, const float* __restrict__ ex_b2,
                const float* __restrict__ base_b,
                float* __restrict__ out)
{
  const int b = blockIdx.x;
  const int tid = threadIdx.x;
  const unsigned short* h1 = H1 + (size_t)b * 3072;
  float p[10];
#pragma unroll
  for (int i = 0; i < 10; i++) p[i] = 0.f;
  {
    const int m = tid;
    const float hr = bf2f(h1[m]);
    p[0] = hr * r_w2[m * 4 + 0];
    p[1] = hr * r_w2[m * 4 + 1];
    p[2] = hr * r_w2[m * 4 + 2];
    p[3] = hr * r_w2[m * 4 + 3];
    const float ha = bf2f(h1[256 + m]);
    p[4] = ha * a_w2[m];
  }
  for (int m = tid; m < 512; m += 256) {
    p[5] += bf2f(h1[512 + m]) * gh_w2[m];
#pragma unroll
    for (int e = 0; e < 4; e++)
      p[6 + e] += bf2f(h1[1024 + e * 512 + m]) * ex_w2[e * 512 + m];
  }

  __shared__ float red[10][4];
  const int lane = tid & 63, wv = tid >> 6;
#pragma unroll
  for (int i = 0; i < 10; i++) {
    const float v = wred(p[i]);
    if (lane == 0) red[i][wv] = v;
  }
  __syncthreads();
  if (tid == 0) {
    float s[10];
#pragma unroll
    for (int i = 0; i < 10; i++) s[i] = red[i][0] + red[i][1] + red[i][2] + red[i][3];
    float lg[4];
#pragma unroll
    for (int e = 0; e < 4; e++) lg[e] = s[e] + r_b2[e];
    const float mx = fmaxf(fmaxf(lg[0], lg[1]), fmaxf(lg[2], lg[3]));
    float den[4]; float dsum = 0.f;
#pragma unroll
    for (int e = 0; e < 4; e++) { den[e] = expf(lg[e] - mx); dsum += den[e]; }
#pragma unroll
    for (int e = 0; e < 4; e++) den[e] /= dsum;
    int i1 = 0;
    for (int e = 1; e < 4; e++) if (den[e] > den[i1]) i1 = e;
    int i2 = -1;
    for (int e = 0; e < 4; e++) { if (e == i1) continue; if (i2 < 0 || den[e] > den[i2]) i2 = e; }
    float eo[4];
#pragma unroll
    for (int e = 0; e < 4; e++) eo[e] = s[6 + e] + ex_b2[e];
    const float v1 = den[i1], v2 = den[i2];
    const float ssum = fmaxf(v1 + v2, 1e-8f);
    const float local = (v1 * eo[i1] + v2 * eo[i2]) / ssum;
    const float glob = s[5] + gh_b2[0];
    const float alpha = 1.0f / (1.0f + expf(-(s[4] + a_b2[0])));
    out[b] = base_y[b] + base_b[0] + alpha * (glob + local);
  }
}

extern "C" void kernel_launch(void* const* d_in, const int* in_sizes, int n_in,
                              void* d_out, int out_size, void* d_ws, size_t ws_size,
                              hipStream_t stream)
{
  const float* x_num  = (const float*)d_in[0];
  const int*   x_cat  = (const int*)d_in[1];
  const float* tok_w  = (const float*)d_in[2];
  const float* tok_b  = (const float*)d_in[3];
  const float* cat_emb= (const float*)d_in[4];
  const float* ln_g   = (const float*)d_in[5];
  const float* ln_b   = (const float*)d_in[6];
  const float* lin0_w = (const float*)d_in[7];
  const float* lin0_b = (const float*)d_in[8];
  const float* sgu_ln_g = (const float*)d_in[9];
  const float* sgu_ln_b = (const float*)d_in[10];
  const float* sgu_w  = (const float*)d_in[11];
  const float* sgu_b  = (const float*)d_in[12];
  const float* lin1_w = (const float*)d_in[13];
  const float* lin1_b = (const float*)d_in[14];
  const float* r_w1   = (const float*)d_in[15];
  const float* r_b1   = (const float*)d_in[16];
  const float* r_w2   = (const float*)d_in[17];
  const float* r_b2   = (const float*)d_in[18];
  const float* a_w1   = (const float*)d_in[19];
  const float* a_b1   = (const float*)d_in[20];
  const float* a_w2   = (const float*)d_in[21];
  const float* a_b2   = (const float*)d_in[22];
  const float* base_w = (const float*)d_in[23];
  const float* base_b = (const float*)d_in[24];
  const float* gh_w1  = (const float*)d_in[25];
  const float* gh_b1  = (const float*)d_in[26];
  const float* gh_w2  = (const float*)d_in[27];
  const float* gh_b2  = (const float*)d_in[28];
  const float* ex_w1  = (const float*)d_in[29];
  const float* ex_b1  = (const float*)d_in[30];
  const float* ex_w2  = (const float*)d_in[31];
  const float* ex_b2  = (const float*)d_in[32];
  (void)in_sizes; (void)n_in; (void)out_size; (void)ws_size;

  char* ws = (char*)d_ws;
  size_t off = 0;
  auto alloc = [&](size_t bytes) { void* p = ws + off; off += (bytes + 255) & ~(size_t)255; return p; };

  unsigned short* w0v  = (unsigned short*)alloc((size_t)768 * 1024 * 2);
  unsigned short* w0u  = (unsigned short*)alloc((size_t)768 * 1024 * 2);
  unsigned short* w1t  = (unsigned short*)alloc((size_t)1024 * 704 * 2);
  unsigned short* wcat = (unsigned short*)alloc((size_t)3072 * 1024 * 2);
  float* bcat          = (float*)alloc((size_t)3072 * 4);
  unsigned short* Amat = (unsigned short*)alloc((size_t)2304 * 1024 * 2);
  float* TAB           = (float*)alloc((size_t)2304 * 768 * 4);
  float* nstat         = (float*)alloc((size_t)101 * 5 * 4);
  float* cstat         = (float*)alloc((size_t)2000 * 2 * 4);
  float* catval        = (float*)alloc((size_t)2001 * 768 * 4);
  float* catsc         = (float*)alloc((size_t)2001 * 2 * 4);
  float* ucon          = (float*)alloc((size_t)704 * 4);
  float* wss_g         = (float*)alloc((size_t)4);
  unsigned short* uv   = (unsigned short*)alloc((size_t)B_SZ * 704 * 2);
  float* xfin          = (float*)alloc((size_t)B_SZ * 1024 * 4);
  float* base_y        = (float*)alloc((size_t)B_SZ * 4);
  unsigned short* hidb = (unsigned short*)alloc((size_t)B_SZ * 1024 * 2);
  unsigned short* H1   = (unsigned short*)alloc((size_t)B_SZ * 3072 * 2);

  const dim3 blk(256);

  PrepArgs J;
  auto setJ = [&](int i, const float* s, unsigned short* d, int ldin, int coff,
                  int Nsrc, int Ksrc, int Kp, int nbx, int nby) {
    J.src[i] = s; J.dst[i] = d; J.ldin[i] = ldin; J.coff[i] = coff;
    J.Nsrc[i] = Nsrc; J.Ksrc[i] = Ksrc; J.Kp[i] = Kp; J.nbx[i] = nbx;
    J.blk0[i + 1] = J.blk0[i] + nbx * nby;
  };
  J.blk0[0] = 0;
  setJ(0, lin0_w, w0v, 1350, 675, 675, 1024, 1024, 16, 12);
  setJ(1, lin0_w, w0u, 1350, 0,   675, 1024, 1024, 16, 12);
  setJ(2, lin1_w, w1t, 1024, 0,  1024,  675,  704, 11, 16);
  setJ(3, r_w1,  wcat,                          256, 0, 256, 1024, 1024, 16, 4);
  setJ(4, a_w1,  wcat + (size_t)256 * 1024,     256, 0, 256, 1024, 1024, 16, 4);
  setJ(5, gh_w1, wcat + (size_t)512 * 1024,     512, 0, 512, 1024, 1024, 16, 8);
  for (int e = 0; e < 4; e++)
    setJ(6 + e, ex_w1 + (size_t)e * 1024 * 512,
         wcat + (size_t)(1024 + e * 512) * 1024, 512, 0, 512, 1024, 1024, 16, 8);

  const int nprep = J.blk0[10] + 576 + 526 + 12;   // 2442
  prep_all<<<nprep, blk, 0, stream>>>(J, tok_w, tok_b, cat_emb, ln_g, ln_b,
      r_b1, a_b1, gh_b1, ex_b1, Amat, nstat, cstat, bcat);

  tab_and_u<<<608, blk, 0, stream>>>(Amat, w0v, TAB, w0u, nstat, tok_w, ln_g, ln_b, lin0_b, ucon);

  cat_rows<<<501, blk, 0, stream>>>(TAB, nstat, cstat, lin0_b, sgu_w, catval, catsc, wss_g);

  fused_v5<<<B_SZ, blk, 0, stream>>>(TAB, nstat, catsc, catval, x_num, x_cat,
      sgu_ln_g, sgu_ln_b, sgu_w, sgu_b, lin0_b, ucon, wss_g, uv);

  gemm64<0><<<16 * 16, blk, 0, stream>>>(uv, 704, w1t, 704,
      lin1_b, tok_w, 16, 1024, 1024, xfin, nullptr);
  ln_gelu_hidden<<<B_SZ / 4, blk, 0, stream>>>(xfin, ln_g, ln_b, base_w, hidb, base_y);
  gemm64<1><<<16 * 48, blk, 0, stream>>>(hidb, 1024, wcat, 1024,
      bcat, nullptr, 48, 3072, 3072, nullptr, H1);

  final_head<<<B_SZ, blk, 0, stream>>>(H1, base_y, r_w2, r_b2, a_w2, a_b2, gh_w2, gh_b2,
                                       ex_w2, ex_b2, base_b, (float*)d_out);
}

// Round 10
// 139.728 us; speedup vs baseline: 1.1852x; 1.1852x over previous
//
#include <hip/hip_runtime.h>
#include <math.h>

#define B_SZ 1024

typedef __attribute__((ext_vector_type(8))) short bf16x8;
typedef __attribute__((ext_vector_type(4))) float f32x4;
typedef __attribute__((ext_vector_type(4))) float floatx4;
typedef __attribute__((ext_vector_type(4))) unsigned short ushortx4;

#define GLOAD16(src, dst) __builtin_amdgcn_global_load_lds( \
    (const __attribute__((address_space(1))) void*)(src), \
    (__attribute__((address_space(3))) void*)(dst), 16, 0, 0)

__device__ __forceinline__ unsigned short f2bf(float f) {
  unsigned int u = __float_as_uint(f);
  u += 0x7fff + ((u >> 16) & 1);
  return (unsigned short)(u >> 16);
}
__device__ __forceinline__ float bf2f(unsigned short b) {
  return __uint_as_float(((unsigned int)b) << 16);
}
__device__ __forceinline__ float gelu_exact(float x) {
  return 0.5f * x * (1.0f + erff(x * 0.70710678118654752f));
}
__device__ __forceinline__ float gelu_fast(float x) {
  const float c0 = 2.3022586f;
  const float c1 = 0.10295465f;
  float z = x * __builtin_fmaf(x * x, c1, c0);
  float e = __builtin_amdgcn_exp2f(z);
  float r = __builtin_amdgcn_rcpf(e + 1.0f);
  return __builtin_fmaf(-x, r, x);
}
__device__ __forceinline__ float wred(float v) {
#pragma unroll
  for (int o = 32; o > 0; o >>= 1) v += __shfl_xor(v, o, 64);
  return v;
}

// ---------------- merged prep: 9 transpose jobs + Amat + stats + bcat ----------------
struct PrepArgs {
  const float* src[9];
  unsigned short* dst[9];
  int ldin[9]; int coff[9]; int Nsrc[9]; int Ksrc[9]; int Kp[9];
  int nbx[9]; int blk0[10];
};

__global__ __launch_bounds__(256)
void prep_all(PrepArgs J,
              const float* __restrict__ tok_w, const float* __restrict__ tok_b,
              const float* __restrict__ cat_emb,
              const float* __restrict__ ln_g, const float* __restrict__ ln_b,
              const float* __restrict__ r_b1, const float* __restrict__ a_b1,
              const float* __restrict__ gh_b1, const float* __restrict__ ex_b1,
              unsigned short* __restrict__ Amat,
              float* __restrict__ nstat, float* __restrict__ cstat,
              float* __restrict__ bcat)
{
  const int bid = blockIdx.x;
  const int tid = threadIdx.x;
  const int lane = tid & 63;
  const int NT = J.blk0[9];                 // 1136
  if (bid < NT) {
    __shared__ float tile[64][65];
    int j = 0;
    while (bid >= J.blk0[j + 1]) ++j;
    const int bx = bid - J.blk0[j];
    const int k0 = (bx % J.nbx[j]) * 64;
    const int n0 = (bx / J.nbx[j]) * 64;
    const float* in = J.src[j];
    unsigned short* out = J.dst[j];
    const int ldin = J.ldin[j], coff = J.coff[j], Nsrc = J.Nsrc[j], Ksrc = J.Ksrc[j], Kp = J.Kp[j];
    const int kx = tid & 63;
    const int ry = tid >> 6;
    for (int r = ry; r < 64; r += 4) {
      const int k = k0 + r;
      const int n = n0 + kx;
      tile[r][kx] = (k < Ksrc && n < Nsrc) ? in[(size_t)k * ldin + coff + n] : 0.f;
    }
    __syncthreads();
    for (int r = ry; r < 64; r += 4) {
      const int n = n0 + r;
      const int k = k0 + kx;
      out[(size_t)n * Kp + k] = f2bf(tile[kx][r]);
    }
  } else if (bid < NT + 576) {
    const int r = (bid - NT) * 4 + (tid >> 6);
    if (r >= 2304) return;
    unsigned short* out = Amat + (size_t)r * 1024;
    for (int k = lane * 4; k < 1024; k += 256) {
      floatx4 g = *(const floatx4*)(ln_g + k);
      floatx4 v;
      if (r <= 100) {
        floatx4 a = *(const floatx4*)(tok_w + (size_t)r * 1024 + k);
#pragma unroll
        for (int q = 0; q < 4; q++) v[q] = a[q] * g[q];
      } else if (r <= 200) {
        floatx4 a = *(const floatx4*)(tok_b + (size_t)(r - 101) * 1024 + k);
#pragma unroll
        for (int q = 0; q < 4; q++) v[q] = a[q] * g[q];
      } else if (r <= 2200) {
        const int j = r - 201;
        const int c = j / 100;
        floatx4 a = *(const floatx4*)(cat_emb + (size_t)j * 1024 + k);
        floatx4 bq = *(const floatx4*)(tok_b + (size_t)(100 + c) * 1024 + k);
#pragma unroll
        for (int q = 0; q < 4; q++) v[q] = (a[q] + bq[q]) * g[q];
      } else if (r == 2201) {
        v = g;
      } else if (r == 2202) {
        v = *(const floatx4*)(ln_b + k);
      } else {
        v[0] = 0.f; v[1] = 0.f; v[2] = 0.f; v[3] = 0.f;
      }
      ushortx4 o;
#pragma unroll
      for (int q = 0; q < 4; q++) o[q] = f2bf(v[q]);
      *(ushortx4*)(out + k) = o;
    }
  } else if (bid < NT + 576 + 526) {
    const int w = (bid - NT - 576) * 4 + (tid >> 6);
    if (w >= 2101) return;
    if (w <= 100) {
      const int t = w;
      const float* wr = tok_w + (size_t)t * 1024;
      const float* br = (t >= 1) ? (tok_b + (size_t)(t - 1) * 1024) : nullptr;
      float sw = 0, sww = 0, sb = 0, sbb = 0, swb = 0;
      for (int k = lane * 4; k < 1024; k += 256) {
        floatx4 a = *(const floatx4*)(wr + k);
#pragma unroll
        for (int q = 0; q < 4; q++) { sw += a[q]; sww += a[q] * a[q]; }
        if (br) {
          floatx4 bq = *(const floatx4*)(br + k);
#pragma unroll
          for (int q = 0; q < 4; q++) { sb += bq[q]; sbb += bq[q] * bq[q]; swb += a[q] * bq[q]; }
        }
      }
      sw = wred(sw); sww = wred(sww); sb = wred(sb); sbb = wred(sbb); swb = wred(swb);
      if (lane == 0) {
        float* ns = nstat + (size_t)t * 5;
        ns[0] = sw; ns[1] = sww; ns[2] = sb; ns[3] = sbb; ns[4] = swb;
      }
    } else {
      const int j = w - 101;
      const int c = j / 100;
      const float* ar = cat_emb + (size_t)j * 1024;
      const float* br = tok_b + (size_t)(100 + c) * 1024;
      float s1 = 0, s2 = 0;
      for (int k = lane * 4; k < 1024; k += 256) {
        floatx4 a = *(const floatx4*)(ar + k);
        floatx4 bq = *(const floatx4*)(br + k);
#pragma unroll
        for (int q = 0; q < 4; q++) { const float v = a[q] + bq[q]; s1 += v; s2 += v * v; }
      }
      s1 = wred(s1); s2 = wred(s2);
      if (lane == 0) { cstat[(size_t)j * 2] = s1; cstat[(size_t)j * 2 + 1] = s2; }
    }
  } else {
    const int n = (bid - NT - 1102) * 256 + tid;
    if (n >= 3072) return;
    float v;
    if (n < 256) v = r_b1[n];
    else if (n < 512) v = a_b1[n - 256];
    else if (n < 1024) v = gh_b1[n - 512];
    else v = ex_b1[n - 1024];
    bcat[n] = v;
  }
}

// ---------------- 64x64-tile bf16 GEMM body ----------------
template<int EPI>
__device__ __forceinline__
void gemm64_body(int bid, const unsigned short* __restrict__ A, long pitchA,
                 const unsigned short* __restrict__ Bw, int K,
                 const float* __restrict__ bias, const float* __restrict__ extra,
                 int NB, int Nvalid, int ldo,
                 float* __restrict__ outf, unsigned short* __restrict__ outb)
{
  __shared__ unsigned short As[64 * 32];
  __shared__ unsigned short Bs[64 * 32];
  const int tid = threadIdx.x, lane = tid & 63, wv = tid >> 6;
  const int nb = bid % NB, mb = bid / NB;
  const int m0 = mb * 64, n0 = nb * 64;
  const int wr = (wv >> 1) << 5, wc = (wv & 1) << 5;
  const int fr = lane & 15, fq = lane >> 4;

  const unsigned short* srcA = A + (size_t)(m0 + (tid >> 2)) * pitchA + ((tid & 3) << 3);
  const unsigned short* srcB = Bw + (size_t)(n0 + (tid >> 2)) * K + ((tid & 3) << 3);

  f32x4 acc[2][2] = {};
  for (int k0 = 0; k0 < K; k0 += 32) {
    __syncthreads();
    GLOAD16(srcA + k0, &As[tid * 8]);
    GLOAD16(srcB + k0, &Bs[tid * 8]);
    __syncthreads();
    bf16x8 af[2], bw_[2];
#pragma unroll
    for (int i = 0; i < 2; i++) {
      af[i]  = *(const bf16x8*)&As[(wr + i * 16 + fr) * 32 + fq * 8];
      bw_[i] = *(const bf16x8*)&Bs[(wc + i * 16 + fr) * 32 + fq * 8];
    }
#pragma unroll
    for (int i = 0; i < 2; i++)
#pragma unroll
      for (int j = 0; j < 2; j++)
        acc[i][j] = __builtin_amdgcn_mfma_f32_16x16x32_bf16(af[i], bw_[j], acc[i][j], 0, 0, 0);
  }

#pragma unroll
  for (int i = 0; i < 2; i++)
#pragma unroll
    for (int j = 0; j < 2; j++) {
      const int n = n0 + wc + j * 16 + fr;
      if (n >= ldo) continue;
      const bool valid = (n < Nvalid);
      const float bv = (EPI == 3) ? 0.f : (valid ? bias[n] : 0.f);
      const float ev = (EPI == 0) ? extra[n] : 0.f;
#pragma unroll
      for (int q = 0; q < 4; q++) {
        const int m = m0 + wr + i * 16 + fq * 4 + q;
        const float a = acc[i][j][q];
        if (EPI == 0) {
          outf[(size_t)m * ldo + n] = a + bv + ev;
        } else if (EPI == 1) {
          outb[(size_t)m * ldo + n] = f2bf(fmaxf(a + bv, 0.f));
        } else {
          outf[(size_t)m * ldo + n] = a;
        }
      }
    }
}

template<int EPI>
__global__ __launch_bounds__(256)
void gemm64(const unsigned short* __restrict__ A, long pitchA,
            const unsigned short* __restrict__ Bw, int K,
            const float* __restrict__ bias, const float* __restrict__ extra,
            int NB, int Nvalid, int ldo,
            float* __restrict__ outf, unsigned short* __restrict__ outb)
{
  gemm64_body<EPI>(blockIdx.x, A, pitchA, Bw, K, bias, extra, NB, Nvalid, ldo, outf, outb);
}

// ---------------- direct ucon GEMV (reads lin0_w row-major, coalesced) ----------------
__device__ __forceinline__
void ucon_body(int bid, const float* __restrict__ lin0_w, const float* __restrict__ nstat,
               const float* __restrict__ tok_w, const float* __restrict__ ln_g,
               const float* __restrict__ ln_b, const float* __restrict__ lin0_b,
               float* __restrict__ ucon)
{
  __shared__ float xk[1024];
  __shared__ float part[4][64];
  const int tid = threadIdx.x;
  const float m = nstat[0] * (1.f / 1024.f);
  const float ex2 = nstat[1] * (1.f / 1024.f);
  const float rs = rsqrtf(ex2 - m * m + 1e-5f);
  for (int k = tid; k < 1024; k += 256)
    xk[k] = bf2f(f2bf((tok_w[k] - m) * rs * ln_g[k] + ln_b[k]));
  __syncthreads();
  const int c = bid * 64 + (tid & 63);
  const int ks = tid >> 6;
  float acc = 0.f;
  for (int k = ks * 256; k < ks * 256 + 256; k++)
    acc = __builtin_fmaf(xk[k], bf2f(f2bf(lin0_w[(size_t)k * 1350 + c])), acc);
  part[ks][tid & 63] = acc;
  __syncthreads();
  if (tid < 64) {
    const int cc = bid * 64 + tid;
    if (cc < 704) {
      const float s = part[0][tid] + part[1][tid] + part[2][tid] + part[3][tid];
      ucon[cc] = (cc < 675) ? gelu_exact(s + lin0_b[cc]) : 0.f;
    }
  }
}

// table GEMM (432 blocks, 64x64) + ucon GEMV (11 blocks)
__global__ __launch_bounds__(256)
void tab_and_u(const unsigned short* __restrict__ Amat, const unsigned short* __restrict__ w0v,
               float* __restrict__ TAB,
               const float* __restrict__ lin0_w, const float* __restrict__ nstat,
               const float* __restrict__ tok_w, const float* __restrict__ ln_g,
               const float* __restrict__ ln_b, const float* __restrict__ lin0_b,
               float* __restrict__ ucon)
{
  if (blockIdx.x < 432)
    gemm64_body<3>(blockIdx.x, Amat, 1024, w0v, 1024, nullptr, nullptr, 12, 768, 768, TAB, nullptr);
  else
    ucon_body(blockIdx.x - 432, lin0_w, nstat, tok_w, ln_g, ln_b, lin0_b, ucon);
}

// ---------------- input-independent rows: 2000 categorical + t0 ----------------
__global__ __launch_bounds__(256)
void cat_rows(const float* __restrict__ TAB, const float* __restrict__ nstat,
              const float* __restrict__ cstat, const float* __restrict__ lin0_b,
              float* __restrict__ catval, float* __restrict__ catsc)
{
  const int r = blockIdx.x * 4 + (threadIdx.x >> 6);
  const int lane = threadIdx.x & 63;
  if (r >= 2001) return;
  float m, ex2;
  const float* T1;
  if (r < 2000) {
    m = cstat[(size_t)r * 2] * (1.f / 1024.f);
    ex2 = cstat[(size_t)r * 2 + 1] * (1.f / 1024.f);
    T1 = TAB + (size_t)(201 + r) * 768;
  } else {
    m = nstat[0] * (1.f / 1024.f);
    ex2 = nstat[1] * (1.f / 1024.f);
    T1 = TAB;
  }
  const float rs = rsqrtf(ex2 - m * m + 1e-5f);
  const float ga = -m * rs;
  const float* R = TAB + (size_t)2201 * 768;
  const float* C = TAB + (size_t)2202 * 768;
  const int dl = lane << 2;
  float s = 0.f, ss = 0.f;
  float* outp = catval + (size_t)r * 768;
#pragma unroll
  for (int ch = 0; ch < 3; ch++) {
    const int d = ch * 256 + dl;
    floatx4 t1 = *(const floatx4*)(T1 + d);
    floatx4 rr = *(const floatx4*)(R + d);
    floatx4 cc = *(const floatx4*)(C + d);
    floatx4 o;
#pragma unroll
    for (int q = 0; q < 4; q++) {
      const int dd = d + q;
      const float c2 = (dd < 675) ? (cc[q] + lin0_b[675 + dd]) : 0.f;
      const float pre = __builtin_fmaf(rs, t1[q], __builtin_fmaf(ga, rr[q], c2));
      const float g = (dd < 675) ? gelu_fast(pre) : 0.f;
      o[q] = g; s += g; ss = __builtin_fmaf(g, g, ss);
    }
    *(floatx4*)(outp + d) = o;
  }
  s = wred(s); ss = wred(ss);
  const float mu = s * (1.f / 675.f);
  const float rho = rsqrtf(ss * (1.f / 675.f) - mu * mu + 1e-5f);
  if (lane == 0) { catsc[(size_t)r * 2] = mu; catsc[(size_t)r * 2 + 1] = rho; }
}

// ---------------- fused v-path v2 (round-6 verbatim): 2 batch rows / block ----------------
__global__ __launch_bounds__(512)
void fused_v2(const float* __restrict__ TAB, const float* __restrict__ nstat,
              const float* __restrict__ catsc, const float* __restrict__ catval,
              const float* __restrict__ x_num, const int* __restrict__ x_cat,
              const float* __restrict__ sgu_ln_g, const float* __restrict__ sgu_ln_b,
              const float* __restrict__ sgu_w, const float* __restrict__ sgu_b,
              const float* __restrict__ lin0_b, const float* __restrict__ ucon,
              unsigned short* __restrict__ uv)
{
  const int b0 = blockIdx.x, b1 = blockIdx.x + 512;
  const int tid = threadIdx.x, lane = tid & 63, wv = tid >> 6;
  __shared__ float Rls[768], Cls[768];
  __shared__ float alf[2][100], bet[2][100], gam[2][100], swt[100];
  __shared__ float wrc[2][21], catkb[2][21];
  __shared__ int catrowS[2][21];
  __shared__ float accw[8][768];
  __shared__ float kbw[2][8];
  __shared__ float wss_s;

  for (int d = tid; d < 768; d += 512) {
    Rls[d] = (d < 675) ? TAB[(size_t)2201 * 768 + d] : 0.f;
    Cls[d] = (d < 675) ? (TAB[(size_t)2202 * 768 + d] + lin0_b[675 + d]) : 0.f;
  }
  if (tid < 200) {
    const int bb = tid / 100, tt = tid % 100;
    const int b = bb ? b1 : b0;
    const float sc = x_num[b * 100 + tt];
    const float* ns = nstat + (size_t)(tt + 1) * 5;
    const float m = (sc * ns[0] + ns[2]) * (1.f / 1024.f);
    const float ex2 = (sc * sc * ns[1] + 2.f * sc * ns[4] + ns[3]) * (1.f / 1024.f);
    const float rs = rsqrtf(ex2 - m * m + 1e-5f);
    alf[bb][tt] = rs * sc; bet[bb][tt] = rs; gam[bb][tt] = -m * rs;
    if (bb == 0) swt[tt] = sgu_w[tt + 1];
  } else if (tid < 242) {
    const int idx = tid - 200;
    const int bb = idx / 21, ii = idx % 21;
    const int b = bb ? b1 : b0;
    int row; float sw;
    if (ii < 20) { row = x_cat[b * 20 + ii] + 100 * ii; sw = sgu_w[101 + ii]; }
    else { row = 2000; sw = sgu_w[0]; }
    const float mu = catsc[(size_t)row * 2], rho = catsc[(size_t)row * 2 + 1];
    const float wr = sw * rho;
    wrc[bb][ii] = wr; catkb[bb][ii] = wr * mu; catrowS[bb][ii] = row;
  } else if (tid >= 256 && tid < 320) {
    float s = (lane < 121 ? sgu_w[lane] : 0.f) + (lane + 64 < 121 ? sgu_w[lane + 64] : 0.f);
    s = wred(s);
    if (lane == 0) wss_s = s;
  }
  __syncthreads();

  float accA[12] = {}, accB[12] = {};
  float kbA = 0.f, kbB = 0.f;
  const int dl = lane << 2;

  for (int i = 0; i < 13; i++) {
    const int tt = wv + 8 * i;
    if (tt >= 100) break;
    const float a0 = alf[0][tt], be0 = bet[0][tt], ga0 = gam[0][tt];
    const float a1 = alf[1][tt], be1 = bet[1][tt], ga1 = gam[1][tt];
    const float* T1 = TAB + (size_t)(tt + 1) * 768;
    const float* T2 = TAB + (size_t)(101 + tt) * 768;
    float s0 = 0.f, ss0 = 0.f, s1 = 0.f, ss1 = 0.f;
    float va[12], vb[12];
#pragma unroll
    for (int ch = 0; ch < 3; ch++) {
      const int d = ch * 256 + dl;
      floatx4 t1 = *(const floatx4*)(T1 + d);
      floatx4 t2 = *(const floatx4*)(T2 + d);
      floatx4 rr = *(const floatx4*)(&Rls[d]);
      floatx4 cc = *(const floatx4*)(&Cls[d]);
#pragma unroll
      for (int q = 0; q < 4; q++) {
        const float pre0 = __builtin_fmaf(a0, t1[q], __builtin_fmaf(be0, t2[q], __builtin_fmaf(ga0, rr[q], cc[q])));
        const float g0 = gelu_fast(pre0);
        va[ch * 4 + q] = g0; s0 += g0; ss0 = __builtin_fmaf(g0, g0, ss0);
        const float pre1 = __builtin_fmaf(a1, t1[q], __builtin_fmaf(be1, t2[q], __builtin_fmaf(ga1, rr[q], cc[q])));
        const float g1 = gelu_fast(pre1);
        vb[ch * 4 + q] = g1; s1 += g1; ss1 = __builtin_fmaf(g1, g1, ss1);
      }
    }
    s0 = wred(s0); ss0 = wred(ss0); s1 = wred(s1); ss1 = wred(ss1);
    const float sw = swt[tt];
    const float mu0 = s0 * (1.f / 675.f);
    const float rho0 = rsqrtf(ss0 * (1.f / 675.f) - mu0 * mu0 + 1e-5f);
    const float w0 = sw * rho0;
    const float mu1 = s1 * (1.f / 675.f);
    const float rho1 = rsqrtf(ss1 * (1.f / 675.f) - mu1 * mu1 + 1e-5f);
    const float w1 = sw * rho1;
#pragma unroll
    for (int q = 0; q < 12; q++) {
      accA[q] = __builtin_fmaf(w0, va[q], accA[q]);
      accB[q] = __builtin_fmaf(w1, vb[q], accB[q]);
    }
    kbA = __builtin_fmaf(w0, mu0, kbA);
    kbB = __builtin_fmaf(w1, mu1, kbB);
  }

  for (int i = 0; i < 3; i++) {
    const int ii = wv + 8 * i;
    if (ii >= 21) break;
    {
      const float wr = wrc[0][ii];
      const float* cv = catval + (size_t)catrowS[0][ii] * 768;
#pragma unroll
      for (int ch = 0; ch < 3; ch++) {
        floatx4 v = *(const floatx4*)(cv + ch * 256 + dl);
#pragma unroll
        for (int q = 0; q < 4; q++) accA[ch * 4 + q] = __builtin_fmaf(wr, v[q], accA[ch * 4 + q]);
      }
    }
    {
      const float wr = wrc[1][ii];
      const float* cv = catval + (size_t)catrowS[1][ii] * 768;
#pragma unroll
      for (int ch = 0; ch < 3; ch++) {
        floatx4 v = *(const floatx4*)(cv + ch * 256 + dl);
#pragma unroll
        for (int q = 0; q < 4; q++) accB[ch * 4 + q] = __builtin_fmaf(wr, v[q], accB[ch * 4 + q]);
      }
    }
  }
  if (lane == 0) { kbw[0][wv] = kbA; kbw[1][wv] = kbB; }

  const float sb0 = sgu_b[0];

#pragma unroll
  for (int ch = 0; ch < 3; ch++)
    *(floatx4*)&accw[wv][ch * 256 + dl] = *(const floatx4*)&accA[ch * 4];
  __syncthreads();
  {
    float kbs = 0.f;
#pragma unroll
    for (int w = 0; w < 8; w++) kbs += kbw[0][w];
#pragma unroll
    for (int i = 0; i < 21; i++) kbs += catkb[0][i];
    const float wss = wss_s;
    for (int d = tid; d < 704; d += 512) {
      unsigned short o = 0;
      if (d < 675) {
        float a = 0.f;
#pragma unroll
        for (int w = 0; w < 8; w++) a += accw[w][d];
        const float v0 = sgu_ln_g[d] * (a - kbs) + sgu_ln_b[d] * wss + sb0;
        o = f2bf(ucon[d] * v0);
      }
      uv[(size_t)b0 * 704 + d] = o;
    }
  }
  __syncthreads();
#pragma unroll
  for (int ch = 0; ch < 3; ch++)
    *(floatx4*)&accw[wv][ch * 256 + dl] = *(const floatx4*)&accB[ch * 4];
  __syncthreads();
  {
    float kbs = 0.f;
#pragma unroll
    for (int w = 0; w < 8; w++) kbs += kbw[1][w];
#pragma unroll
    for (int i = 0; i < 21; i++) kbs += catkb[1][i];
    const float wss = wss_s;
    for (int d = tid; d < 704; d += 512) {
      unsigned short o = 0;
      if (d < 675) {
        float a = 0.f;
#pragma unroll
        for (int w = 0; w < 8; w++) a += accw[w][d];
        const float v0 = sgu_ln_g[d] * (a - kbs) + sgu_ln_b[d] * wss + sb0;
        o = f2bf(ucon[d] * v0);
      }
      uv[(size_t)b1 * 704 + d] = o;
    }
  }
}

// ---------------- LN + gelu -> hidden bf16 + fused base dot ----------------
__global__ __launch_bounds__(256)
void ln_gelu_hidden(const float* __restrict__ xfin,
                    const float* __restrict__ ln_g, const float* __restrict__ ln_b,
                    const float* __restrict__ base_w,
                    unsigned short* __restrict__ hid_bf, float* __restrict__ base_y)
{
  const int w = (blockIdx.x * 256 + threadIdx.x) >> 6;
  const int lane = threadIdx.x & 63;
  if (w >= B_SZ) return;
  const float* row = xfin + (size_t)w * 1024;
  float s = 0.f, ss = 0.f;
  for (int k = lane; k < 1024; k += 64) { float v = row[k]; s += v; ss += v * v; }
  s = wred(s); ss = wred(ss);
  const float m = s * (1.f / 1024.f);
  const float var = ss * (1.f / 1024.f) - m * m;
  const float rs = rsqrtf(var + 1e-5f);
  float bacc = 0.f;
  for (int k = lane; k < 1024; k += 64) {
    float v = gelu_fast((row[k] - m) * rs * ln_g[k] + ln_b[k]);
    hid_bf[(size_t)w * 1024 + k] = f2bf(v);
    bacc = __builtin_fmaf(v, base_w[k], bacc);
  }
  bacc = wred(bacc);
  if (lane == 0) base_y[w] = bacc;
}

// ---------------- per-row finale ----------------
__global__ __launch_bounds__(256)
void final_head(const unsigned short* __restrict__ H1, const float* __restrict__ base_y,
                const float* __restrict__ r_w2, const float* __restrict__ r_b2,
                const float* __restrict__ a_w2, const float* __restrict__ a_b2,
                const float* __restrict__ gh_w2, const float* __restrict__ gh_b2,
                const float* __restrict__ ex_w2, const float* __restrict__ ex_b2,
                const float* __restrict__ base_b,
                float* __restrict__ out)
{
  const int b = blockIdx.x;
  const int tid = threadIdx.x;
  const unsigned short* h1 = H1 + (size_t)b * 3072;
  float p[10];
#pragma unroll
  for (int i = 0; i < 10; i++) p[i] = 0.f;
  {
    const int m = tid;
    const float hr = bf2f(h1[m]);
    p[0] = hr * r_w2[m * 4 + 0];
    p[1] = hr * r_w2[m * 4 + 1];
    p[2] = hr * r_w2[m * 4 + 2];
    p[3] = hr * r_w2[m * 4 + 3];
    const float ha = bf2f(h1[256 + m]);
    p[4] = ha * a_w2[m];
  }
  for (int m = tid; m < 512; m += 256) {
    p[5] += bf2f(h1[512 + m]) * gh_w2[m];
#pragma unroll
    for (int e = 0; e < 4; e++)
      p[6 + e] += bf2f(h1[1024 + e * 512 + m]) * ex_w2[e * 512 + m];
  }

  __shared__ float red[10][4];
  const int lane = tid & 63, wv = tid >> 6;
#pragma unroll
  for (int i = 0; i < 10; i++) {
    const float v = wred(p[i]);
    if (lane == 0) red[i][wv] = v;
  }
  __syncthreads();
  if (tid == 0) {
    float s[10];
#pragma unroll
    for (int i = 0; i < 10; i++) s[i] = red[i][0] + red[i][1] + red[i][2] + red[i][3];
    float lg[4];
#pragma unroll
    for (int e = 0; e < 4; e++) lg[e] = s[e] + r_b2[e];
    const float mx = fmaxf(fmaxf(lg[0], lg[1]), fmaxf(lg[2], lg[3]));
    float den[4]; float dsum = 0.f;
#pragma unroll
    for (int e = 0; e < 4; e++) { den[e] = expf(lg[e] - mx); dsum += den[e]; }
#pragma unroll
    for (int e = 0; e < 4; e++) den[e] /= dsum;
    int i1 = 0;
    for (int e = 1; e < 4; e++) if (den[e] > den[i1]) i1 = e;
    int i2 = -1;
    for (int e = 0; e < 4; e++) { if (e == i1) continue; if (i2 < 0 || den[e] > den[i2]) i2 = e; }
    float eo[4];
#pragma unroll
    for (int e = 0; e < 4; e++) eo[e] = s[6 + e] + ex_b2[e];
    const float v1 = den[i1], v2 = den[i2];
    const float ssum = fmaxf(v1 + v2, 1e-8f);
    const float local = (v1 * eo[i1] + v2 * eo[i2]) / ssum;
    const float glob = s[5] + gh_b2[0];
    const float alpha = 1.0f / (1.0f + expf(-(s[4] + a_b2[0])));
    out[b] = base_y[b] + base_b[0] + alpha * (glob + local);
  }
}

extern "C" void kernel_launch(void* const* d_in, const int* in_sizes, int n_in,
                              void* d_out, int out_size, void* d_ws, size_t ws_size,
                              hipStream_t stream)
{
  const float* x_num  = (const float*)d_in[0];
  const int*   x_cat  = (const int*)d_in[1];
  const float* tok_w  = (const float*)d_in[2];
  const float* tok_b  = (const float*)d_in[3];
  const float* cat_emb= (const float*)d_in[4];
  const float* ln_g   = (const float*)d_in[5];
  const float* ln_b   = (const float*)d_in[6];
  const float* lin0_w = (const float*)d_in[7];
  const float* lin0_b = (const float*)d_in[8];
  const float* sgu_ln_g = (const float*)d_in[9];
  const float* sgu_ln_b = (const float*)d_in[10];
  const float* sgu_w  = (const float*)d_in[11];
  const float* sgu_b  = (const float*)d_in[12];
  const float* lin1_w = (const float*)d_in[13];
  const float* lin1_b = (const float*)d_in[14];
  const float* r_w1   = (const float*)d_in[15];
  const float* r_b1   = (const float*)d_in[16];
  const float* r_w2   = (const float*)d_in[17];
  const float* r_b2   = (const float*)d_in[18];
  const float* a_w1   = (const float*)d_in[19];
  const float* a_b1   = (const float*)d_in[20];
  const float* a_w2   = (const float*)d_in[21];
  const float* a_b2   = (const float*)d_in[22];
  const float* base_w = (const float*)d_in[23];
  const float* base_b = (const float*)d_in[24];
  const float* gh_w1  = (const float*)d_in[25];
  const float* gh_b1  = (const float*)d_in[26];
  const float* gh_w2  = (const float*)d_in[27];
  const float* gh_b2  = (const float*)d_in[28];
  const float* ex_w1  = (const float*)d_in[29];
  const float* ex_b1  = (const float*)d_in[30];
  const float* ex_w2  = (const float*)d_in[31];
  const float* ex_b2  = (const float*)d_in[32];
  (void)in_sizes; (void)n_in; (void)out_size; (void)ws_size;

  char* ws = (char*)d_ws;
  size_t off = 0;
  auto alloc = [&](size_t bytes) { void* p = ws + off; off += (bytes + 255) & ~(size_t)255; return p; };

  unsigned short* w0v  = (unsigned short*)alloc((size_t)768 * 1024 * 2);
  unsigned short* w1t  = (unsigned short*)alloc((size_t)1024 * 704 * 2);
  unsigned short* wcat = (unsigned short*)alloc((size_t)3072 * 1024 * 2);
  float* bcat          = (float*)alloc((size_t)3072 * 4);
  unsigned short* Amat = (unsigned short*)alloc((size_t)2304 * 1024 * 2);
  float* TAB           = (float*)alloc((size_t)2304 * 768 * 4);
  float* nstat         = (float*)alloc((size_t)101 * 5 * 4);
  float* cstat         = (float*)alloc((size_t)2000 * 2 * 4);
  float* catval        = (float*)alloc((size_t)2001 * 768 * 4);
  float* catsc         = (float*)alloc((size_t)2001 * 2 * 4);
  float* ucon          = (float*)alloc((size_t)704 * 4);
  unsigned short* uv   = (unsigned short*)alloc((size_t)B_SZ * 704 * 2);
  float* xfin          = (float*)alloc((size_t)B_SZ * 1024 * 4);
  float* base_y        = (float*)alloc((size_t)B_SZ * 4);
  unsigned short* hidb = (unsigned short*)alloc((size_t)B_SZ * 1024 * 2);
  unsigned short* H1   = (unsigned short*)alloc((size_t)B_SZ * 3072 * 2);

  const dim3 blk(256);

  PrepArgs J;
  auto setJ = [&](int i, const float* s, unsigned short* d, int ldin, int coff,
                  int Nsrc, int Ksrc, int Kp, int nbx, int nby) {
    J.src[i] = s; J.dst[i] = d; J.ldin[i] = ldin; J.coff[i] = coff;
    J.Nsrc[i] = Nsrc; J.Ksrc[i] = Ksrc; J.Kp[i] = Kp; J.nbx[i] = nbx;
    J.blk0[i + 1] = J.blk0[i] + nbx * nby;
  };
  J.blk0[0] = 0;
  setJ(0, lin0_w, w0v, 1350, 675, 675, 1024, 1024, 16, 12);
  setJ(1, lin1_w, w1t, 1024, 0,  1024,  675,  704, 11, 16);
  setJ(2, r_w1,  wcat,                          256, 0, 256, 1024, 1024, 16, 4);
  setJ(3, a_w1,  wcat + (size_t)256 * 1024,     256, 0, 256, 1024, 1024, 16, 4);
  setJ(4, gh_w1, wcat + (size_t)512 * 1024,     512, 0, 512, 1024, 1024, 16, 8);
  for (int e = 0; e < 4; e++)
    setJ(5 + e, ex_w1 + (size_t)e * 1024 * 512,
         wcat + (size_t)(1024 + e * 512) * 1024, 512, 0, 512, 1024, 1024, 16, 8);

  const int nprep = J.blk0[9] + 576 + 526 + 12;   // 1136 + 1114 = 2250
  prep_all<<<nprep, blk, 0, stream>>>(J, tok_w, tok_b, cat_emb, ln_g, ln_b,
      r_b1, a_b1, gh_b1, ex_b1, Amat, nstat, cstat, bcat);

  tab_and_u<<<443, blk, 0, stream>>>(Amat, w0v, TAB, lin0_w, nstat, tok_w, ln_g, ln_b, lin0_b, ucon);

  cat_rows<<<501, blk, 0, stream>>>(TAB, nstat, cstat, lin0_b, catval, catsc);

  fused_v2<<<512, dim3(512), 0, stream>>>(TAB, nstat, catsc, catval, x_num, x_cat,
      sgu_ln_g, sgu_ln_b, sgu_w, sgu_b, lin0_b, ucon, uv);

  gemm64<0><<<16 * 16, blk, 0, stream>>>(uv, 704, w1t, 704,
      lin1_b, tok_w, 16, 1024, 1024, xfin, nullptr);
  ln_gelu_hidden<<<B_SZ / 4, blk, 0, stream>>>(xfin, ln_g, ln_b, base_w, hidb, base_y);
  gemm64<1><<<16 * 48, blk, 0, stream>>>(hidb, 1024, wcat, 1024,
      bcat, nullptr, 48, 3072, 3072, nullptr, H1);

  final_head<<<B_SZ, blk, 0, stream>>>(H1, base_y, r_w2, r_b2, a_w2, a_b2, gh_w2, gh_b2,
                                       ex_w2, ex_b2, base_b, (float*)d_out);
}